// Round 6
// baseline (220.766 us; speedup 1.0000x reference)
//
#include <hip/hip_runtime.h>

typedef __attribute__((ext_vector_type(8))) short short8;
typedef __attribute__((ext_vector_type(4))) float f32x4;

#define B_SZ 32
#define C_IN 512
#define C8V 64
#define LSEQ 1024
#define OUT_ELEMS (B_SZ * C_IN * LSEQ)

__device__ inline unsigned short bf16_rn(float f) {
  unsigned int u = __float_as_uint(f);
  unsigned int r = 0x7FFFu + ((u >> 16) & 1u);
  return (unsigned short)((u + r) >> 16);
}
__device__ inline float bf16_to_f32(unsigned short h) {
  return __uint_as_float(((unsigned int)h) << 16);
}
__device__ inline void split_bf16(float f, unsigned short &hi, unsigned short &lo) {
  hi = bf16_rn(f);
  lo = bf16_rn(f - bf16_to_f32(hi));
}

// ---------- Kernel 0: pre-split weights into bf16 hi/lo planes ----------
__global__ __launch_bounds__(256) void split_weights(
    const float* __restrict__ Wq, const float* __restrict__ Wk, const float* __restrict__ Wv,
    unsigned short* __restrict__ Wqh, unsigned short* __restrict__ Wql,
    unsigned short* __restrict__ Wkh, unsigned short* __restrict__ Wkl,
    unsigned short* __restrict__ Wvh)
{
  int i = (blockIdx.x * 256 + threadIdx.x) * 4;
  if (i < 262144) {
    f32x4 f = *(const f32x4*)&Wv[i];
    #pragma unroll
    for (int j = 0; j < 4; ++j) Wvh[i + j] = bf16_rn(f[j]);
  } else if (i < 294912) {
    int k = i - 262144;
    f32x4 f = *(const f32x4*)&Wq[k];
    #pragma unroll
    for (int j = 0; j < 4; ++j) { unsigned short h, l; split_bf16(f[j], h, l); Wqh[k+j] = h; Wql[k+j] = l; }
  } else {
    int k = i - 294912;
    f32x4 f = *(const f32x4*)&Wk[k];
    #pragma unroll
    for (int j = 0; j < 4; ++j) { unsigned short h, l; split_bf16(f[j], h, l); Wkh[k+j] = h; Wkl[k+j] = l; }
  }
}

// ---------- Kernel T: x [b][c][l] f32 -> xT hi/lo [b][l][c] bf16 ----------
// grid (16 lt, 8 ct, 32 b); tile 64c x 64l per block.
__global__ __launch_bounds__(256) void transpose_split(
    const float* __restrict__ x,
    unsigned short* __restrict__ xth, unsigned short* __restrict__ xtl)
{
  const int lt = blockIdx.x, ct = blockIdx.y, b = blockIdx.z;
  const int tid = threadIdx.x;
  __shared__ float xs[64 * 68];

  #pragma unroll
  for (int i = 0; i < 4; ++i) {
    int idx = tid + i * 256;
    int c = idx >> 4, l4 = idx & 15;
    f32x4 v = *(const f32x4*)&x[((long)b*C_IN + ct*64 + c)*LSEQ + lt*64 + l4*4];
    *(f32x4*)&xs[c*68 + l4*4] = v;
  }
  __syncthreads();
  const int l = tid >> 2, seg = tid & 3;
  unsigned short hbuf[16], lbuf[16];
  #pragma unroll
  for (int i = 0; i < 16; ++i)
    split_bf16(xs[(seg*16 + i)*68 + l], hbuf[i], lbuf[i]);
  long base = ((long)b*LSEQ + lt*64 + l)*C_IN + ct*64 + seg*16;
  *(short8*)&xth[base]     = *(const short8*)&hbuf[0];
  *(short8*)&xth[base + 8] = *(const short8*)&hbuf[8];
  *(short8*)&xtl[base]     = *(const short8*)&lbuf[0];
  *(short8*)&xtl[base + 8] = *(const short8*)&lbuf[8];
}

// ---------- Kernel 1: q,k projection (pure bf16 GEMM) ----------
// tile: M=128 (64 q + 64 k) x N=64 l, K-step 64. grid (16 nt, 32 b).
__global__ __launch_bounds__(256, 2) void qk_proj(
    const unsigned short* __restrict__ xth, const unsigned short* __restrict__ xtl,
    const unsigned short* __restrict__ Wqh, const unsigned short* __restrict__ Wql,
    const unsigned short* __restrict__ Wkh, const unsigned short* __restrict__ Wkl,
    const float* __restrict__ bq, const float* __restrict__ bk,
    unsigned short* __restrict__ qh, unsigned short* __restrict__ ql,
    unsigned short* __restrict__ kh, unsigned short* __restrict__ kl)
{
  const int nt = blockIdx.x;
  const int b  = blockIdx.y;
  const int tid = threadIdx.x;
  const int wave = tid >> 6, lane = tid & 63;
  const int wr = wave >> 1, wc = wave & 1;
  const int g = lane >> 4, ln = lane & 15;

  __shared__ char smem[49152];
  unsigned short* Ah = (unsigned short*)smem;      // [128][64] swizzled
  unsigned short* Al = Ah + 8192;
  unsigned short* Bh = Al + 8192;                  // [64][64] swizzled
  unsigned short* Bl = Bh + 4096;

  const int rb = tid >> 3, jj = tid & 7;           // rb 0..31, jj 0..7
  const int dst0 = rb*64 + ((jj ^ (rb & 7)) << 3);
  const long xbase = ((long)b*LSEQ + nt*64 + rb)*C_IN + jj*8;

  short8 rAh[4], rAl[4], rBh[2], rBl[2];
  // prefetch chunk 0: A rows rb+{0,32}=Wq, rb+{64,96}=Wk rows rb+{0,32}
  rAh[0] = *(const short8*)&Wqh[rb*C_IN + jj*8];
  rAh[1] = *(const short8*)&Wqh[(rb+32)*C_IN + jj*8];
  rAh[2] = *(const short8*)&Wkh[rb*C_IN + jj*8];
  rAh[3] = *(const short8*)&Wkh[(rb+32)*C_IN + jj*8];
  rAl[0] = *(const short8*)&Wql[rb*C_IN + jj*8];
  rAl[1] = *(const short8*)&Wql[(rb+32)*C_IN + jj*8];
  rAl[2] = *(const short8*)&Wkl[rb*C_IN + jj*8];
  rAl[3] = *(const short8*)&Wkl[(rb+32)*C_IN + jj*8];
  rBh[0] = *(const short8*)&xth[xbase];
  rBh[1] = *(const short8*)&xth[xbase + 32*C_IN];
  rBl[0] = *(const short8*)&xtl[xbase];
  rBl[1] = *(const short8*)&xtl[xbase + 32*C_IN];

  f32x4 acc[4][2] = {};

  for (int kb = 0; kb < 8; ++kb) {
    __syncthreads();
    #pragma unroll
    for (int j = 0; j < 4; ++j) {
      *(short8*)&Ah[dst0 + j*2048] = rAh[j];
      *(short8*)&Al[dst0 + j*2048] = rAl[j];
    }
    #pragma unroll
    for (int j = 0; j < 2; ++j) {
      *(short8*)&Bh[dst0 + j*2048] = rBh[j];
      *(short8*)&Bl[dst0 + j*2048] = rBl[j];
    }
    __syncthreads();
    if (kb < 7) {
      int ko = (kb+1)*64;
      rAh[0] = *(const short8*)&Wqh[rb*C_IN + ko + jj*8];
      rAh[1] = *(const short8*)&Wqh[(rb+32)*C_IN + ko + jj*8];
      rAh[2] = *(const short8*)&Wkh[rb*C_IN + ko + jj*8];
      rAh[3] = *(const short8*)&Wkh[(rb+32)*C_IN + ko + jj*8];
      rAl[0] = *(const short8*)&Wql[rb*C_IN + ko + jj*8];
      rAl[1] = *(const short8*)&Wql[(rb+32)*C_IN + ko + jj*8];
      rAl[2] = *(const short8*)&Wkl[rb*C_IN + ko + jj*8];
      rAl[3] = *(const short8*)&Wkl[(rb+32)*C_IN + ko + jj*8];
      rBh[0] = *(const short8*)&xth[xbase + ko];
      rBh[1] = *(const short8*)&xth[xbase + 32*C_IN + ko];
      rBl[0] = *(const short8*)&xtl[xbase + ko];
      rBl[1] = *(const short8*)&xtl[xbase + 32*C_IN + ko];
    }
    #pragma unroll
    for (int ks = 0; ks < 2; ++ks) {
      int s = ((ks*4 + g) ^ (ln & 7)) << 3;
      short8 bhf[2], blf[2];
      #pragma unroll
      for (int ni = 0; ni < 2; ++ni) {
        int cr = wc*32 + ni*16 + ln;
        bhf[ni] = *(const short8*)&Bh[cr*64 + s];
        blf[ni] = *(const short8*)&Bl[cr*64 + s];
      }
      #pragma unroll
      for (int mi = 0; mi < 4; ++mi) {
        int ar = wr*64 + mi*16 + ln;
        short8 ahf = *(const short8*)&Ah[ar*64 + s];
        short8 alf = *(const short8*)&Al[ar*64 + s];
        #pragma unroll
        for (int ni = 0; ni < 2; ++ni) {
          acc[mi][ni] = __builtin_amdgcn_mfma_f32_16x16x32_bf16(ahf, bhf[ni], acc[mi][ni], 0,0,0);
          acc[mi][ni] = __builtin_amdgcn_mfma_f32_16x16x32_bf16(ahf, blf[ni], acc[mi][ni], 0,0,0);
          acc[mi][ni] = __builtin_amdgcn_mfma_f32_16x16x32_bf16(alf, bhf[ni], acc[mi][ni], 0,0,0);
        }
      }
    }
  }
  __syncthreads();
  unsigned short* Trh = (unsigned short*)smem;     // [64 l][136]
  unsigned short* Trl = Trh + 64*136;
  #pragma unroll
  for (int mi = 0; mi < 4; ++mi)
    #pragma unroll
    for (int ni = 0; ni < 2; ++ni)
      #pragma unroll
      for (int j = 0; j < 4; ++j) {
        int rloc = wr*64 + mi*16 + g*4 + j;
        int cloc = wc*32 + ni*16 + ln;
        float bias = (rloc < 64) ? bq[rloc] : bk[rloc - 64];
        unsigned short hi, lo; split_bf16(acc[mi][ni][j] + bias, hi, lo);
        Trh[cloc*136 + rloc] = hi;
        Trl[cloc*136 + rloc] = lo;
      }
  __syncthreads();
  #pragma unroll
  for (int i = 0; i < 4; ++i) {
    int idx = tid + i*256;
    int l = idx >> 4, s = idx & 15;
    long row = ((long)b*LSEQ + nt*64 + l) * 64;
    short8 h  = *(const short8*)&Trh[l*136 + s*8];
    short8 lo = *(const short8*)&Trl[l*136 + s*8];
    if (s < 8) { *(short8*)&qh[row + s*8] = h;      *(short8*)&ql[row + s*8] = lo; }
    else       { *(short8*)&kh[row + (s-8)*8] = h;  *(short8*)&kl[row + (s-8)*8] = lo; }
  }
}

// ---------- Kernel 2: v projection (pure bf16 GEMM) -> bf16 [b][c][l] ----------
// tile 128c x 128l, K-step 64. grid (8 lt, 4 ct, 32 b).
__global__ __launch_bounds__(256, 2) void v_proj(
    const unsigned short* __restrict__ xth,
    const unsigned short* __restrict__ Wvh,
    const float* __restrict__ bv,
    unsigned short* __restrict__ vws)
{
  const int lt = blockIdx.x;
  const int ct = blockIdx.y;
  const int b  = blockIdx.z;
  const int tid = threadIdx.x;
  const int wave = tid >> 6, lane = tid & 63;
  const int wr = wave >> 1, wc = wave & 1;
  const int g = lane >> 4, ln = lane & 15;

  __shared__ char smem[34816];
  unsigned short* Ahs = (unsigned short*)smem;     // [128][64] swizzled
  unsigned short* Bhs = Ahs + 8192;                // [128][64] swizzled

  const int rb = tid >> 3, jj = tid & 7;
  const int dst0 = rb*64 + ((jj ^ (rb & 7)) << 3);
  const long wbase = (long)(ct*128 + rb)*C_IN + jj*8;
  const long xbase = ((long)b*LSEQ + lt*128 + rb)*C_IN + jj*8;

  short8 rA[4], rB[4];
  #pragma unroll
  for (int j = 0; j < 4; ++j) {
    rA[j] = *(const short8*)&Wvh[wbase + (long)j*32*C_IN];
    rB[j] = *(const short8*)&xth[xbase + (long)j*32*C_IN];
  }

  f32x4 acc[4][4] = {};

  for (int kb = 0; kb < 8; ++kb) {
    __syncthreads();
    #pragma unroll
    for (int j = 0; j < 4; ++j) {
      *(short8*)&Ahs[dst0 + j*2048] = rA[j];
      *(short8*)&Bhs[dst0 + j*2048] = rB[j];
    }
    __syncthreads();
    if (kb < 7) {
      int ko = (kb+1)*64;
      #pragma unroll
      for (int j = 0; j < 4; ++j) {
        rA[j] = *(const short8*)&Wvh[wbase + (long)j*32*C_IN + ko];
        rB[j] = *(const short8*)&xth[xbase + (long)j*32*C_IN + ko];
      }
    }
    #pragma unroll
    for (int ks = 0; ks < 2; ++ks) {
      int s = ((ks*4 + g) ^ (ln & 7)) << 3;
      short8 bf[4];
      #pragma unroll
      for (int ni = 0; ni < 4; ++ni) {
        int cr = wc*64 + ni*16 + ln;
        bf[ni] = *(const short8*)&Bhs[cr*64 + s];
      }
      #pragma unroll
      for (int mi = 0; mi < 4; ++mi) {
        int ar = wr*64 + mi*16 + ln;
        short8 af = *(const short8*)&Ahs[ar*64 + s];
        #pragma unroll
        for (int ni = 0; ni < 4; ++ni)
          acc[mi][ni] = __builtin_amdgcn_mfma_f32_16x16x32_bf16(af, bf[ni], acc[mi][ni], 0,0,0);
      }
    }
  }
  __syncthreads();
  unsigned short* Tr = (unsigned short*)smem;      // [128 c][136]
  #pragma unroll
  for (int mi = 0; mi < 4; ++mi)
    #pragma unroll
    for (int ni = 0; ni < 4; ++ni)
      #pragma unroll
      for (int j = 0; j < 4; ++j) {
        int rloc = wr*64 + mi*16 + g*4 + j;
        int cloc = wc*64 + ni*16 + ln;
        Tr[rloc*136 + cloc] = bf16_rn(acc[mi][ni][j] + bv[ct*128 + rloc]);
      }
  __syncthreads();
  #pragma unroll
  for (int i = 0; i < 8; ++i) {
    int idx = tid + i*256;
    int c = idx >> 4, s = idx & 15;
    *(short8*)&vws[((long)b*C_IN + ct*128 + c)*LSEQ + lt*128 + s*8] =
      *(const short8*)&Tr[c*136 + s*8];
  }
}

// ---------- Kernel 3: energy + softmax -> attn f32 (d_out) + P bf16 copy ----------
__global__ __launch_bounds__(256, 2) void energy_softmax(
    const unsigned short* __restrict__ qh, const unsigned short* __restrict__ ql,
    const unsigned short* __restrict__ kh, const unsigned short* __restrict__ kl,
    float* __restrict__ attn, unsigned short* __restrict__ pbuf)
{
  const int lt = blockIdx.x;
  const int b  = blockIdx.y;
  const int tid = threadIdx.x;
  const int wave = tid >> 6, lane = tid & 63;
  const int g = lane >> 4, ln = lane & 15;

  __shared__ unsigned short Ksm[16640];   // Kh[8192] + Kl[8192]; reused as Pb[16][1032]
  __shared__ float redM[4][16];
  __shared__ float redS[4][16];
  unsigned short* Kh = Ksm;
  unsigned short* Kl = Ksm + 8192;

  short8 ah[2], al[2];
  {
    long qrow = ((long)b*LSEQ + lt*16 + ln) * 64;
    #pragma unroll
    for (int ks = 0; ks < 2; ++ks) {
      ah[ks] = *(const short8*)&qh[qrow + ks*32 + g*8];
      al[ks] = *(const short8*)&ql[qrow + ks*32 + g*8];
    }
  }

  const int rb = tid >> 3, jj = tid & 7;
  const int dst0 = rb*64 + ((jj ^ (rb & 7)) << 3);
  const long kbase = ((long)b*LSEQ + rb)*64 + jj*8;

  short8 rkh[4], rkl[4];
  #pragma unroll
  for (int j = 0; j < 4; ++j) {
    rkh[j] = *(const short8*)&kh[kbase + j*2048];
    rkl[j] = *(const short8*)&kl[kbase + j*2048];
  }

  f32x4 acc[8][2] = {};
  #pragma unroll
  for (int c = 0; c < 8; ++c) {
    __syncthreads();
    #pragma unroll
    for (int j = 0; j < 4; ++j) {
      *(short8*)&Kh[dst0 + j*2048] = rkh[j];
      *(short8*)&Kl[dst0 + j*2048] = rkl[j];
    }
    __syncthreads();
    if (c < 7) {
      #pragma unroll
      for (int j = 0; j < 4; ++j) {
        rkh[j] = *(const short8*)&kh[kbase + (long)(c+1)*8192 + j*2048];
        rkl[j] = *(const short8*)&kl[kbase + (long)(c+1)*8192 + j*2048];
      }
    }
    #pragma unroll
    for (int fq = 0; fq < 2; ++fq) {
      int mloc = wave*32 + fq*16 + ln;
      #pragma unroll
      for (int ks = 0; ks < 2; ++ks) {
        int s = ((ks*4 + g) ^ (mloc & 7)) << 3;
        short8 bh = *(const short8*)&Kh[mloc*64 + s];
        short8 bl = *(const short8*)&Kl[mloc*64 + s];
        acc[c][fq] = __builtin_amdgcn_mfma_f32_16x16x32_bf16(ah[ks], bh, acc[c][fq], 0,0,0);
        acc[c][fq] = __builtin_amdgcn_mfma_f32_16x16x32_bf16(ah[ks], bl, acc[c][fq], 0,0,0);
        acc[c][fq] = __builtin_amdgcn_mfma_f32_16x16x32_bf16(al[ks], bh, acc[c][fq], 0,0,0);
      }
    }
  }

  float mx[4];
  #pragma unroll
  for (int j = 0; j < 4; ++j) {
    float m = -1e30f;
    #pragma unroll
    for (int c = 0; c < 8; ++c)
      #pragma unroll
      for (int fq = 0; fq < 2; ++fq) m = fmaxf(m, acc[c][fq][j]);
    #pragma unroll
    for (int off = 1; off < 16; off <<= 1) m = fmaxf(m, __shfl_xor(m, off));
    mx[j] = m;
  }
  if (ln == 0) {
    #pragma unroll
    for (int j = 0; j < 4; ++j) redM[wave][g*4+j] = mx[j];
  }
  __syncthreads();
  #pragma unroll
  for (int j = 0; j < 4; ++j) {
    float m = redM[0][g*4+j];
    #pragma unroll
    for (int w = 1; w < 4; ++w) m = fmaxf(m, redM[w][g*4+j]);
    mx[j] = m;
  }
  float sm[4];
  #pragma unroll
  for (int j = 0; j < 4; ++j) {
    float s = 0.f;
    #pragma unroll
    for (int c = 0; c < 8; ++c)
      #pragma unroll
      for (int fq = 0; fq < 2; ++fq) {
        float p = expf(acc[c][fq][j] - mx[j]);
        acc[c][fq][j] = p;
        s += p;
      }
    #pragma unroll
    for (int off = 1; off < 16; off <<= 1) s += __shfl_xor(s, off);
    sm[j] = s;
  }
  if (ln == 0) {
    #pragma unroll
    for (int j = 0; j < 4; ++j) redS[wave][g*4+j] = sm[j];
  }
  __syncthreads();
  #pragma unroll
  for (int j = 0; j < 4; ++j) {
    float s = redS[0][g*4+j];
    #pragma unroll
    for (int w = 1; w < 4; ++w) s += redS[w][g*4+j];
    sm[j] = 1.0f / s;
  }

  unsigned short* Pb = Ksm;              // [16][1032]
  __syncthreads();
  #pragma unroll
  for (int c = 0; c < 8; ++c)
    #pragma unroll
    for (int fq = 0; fq < 2; ++fq) {
      int m0 = c*128 + wave*32 + fq*16 + ln;
      #pragma unroll
      for (int j = 0; j < 4; ++j)
        Pb[(g*4+j)*1032 + m0] = bf16_rn(acc[c][fq][j] * sm[j]);
    }
  __syncthreads();
  #pragma unroll
  for (int u = 0; u < 8; ++u) {
    int cid = tid + u*256;
    int row = cid >> 7, col = (cid & 127) * 8;
    short8 v = *(const short8*)&Pb[row*1032 + col];
    long gro = ((long)b*LSEQ + lt*16 + row)*LSEQ + col;
    *(short8*)&pbuf[gro] = v;
    f32x4 f0, f1;
    #pragma unroll
    for (int i = 0; i < 4; ++i) {
      f0[i] = bf16_to_f32((unsigned short)v[i]);
      f1[i] = bf16_to_f32((unsigned short)v[i+4]);
    }
    *(f32x4*)&attn[gro] = f0;
    *(f32x4*)&attn[gro + 4] = f1;
  }
}

// ---------- Kernel 4: out = gamma * (V @ P^T) + x ----------
__global__ __launch_bounds__(256, 2) void pv_out(
    const unsigned short* __restrict__ vws,
    const unsigned short* __restrict__ pbuf,
    const float* __restrict__ x,
    const float* __restrict__ gamma,
    float* __restrict__ out)
{
  const int lt = blockIdx.x;
  const int ct = blockIdx.y;
  const int b  = blockIdx.z;
  const int tid = threadIdx.x;
  const int wave = tid >> 6, lane = tid & 63;
  const int wr = wave >> 1, wc = wave & 1;
  const int g = lane >> 4, ln = lane & 15;

  __shared__ char smem[34816];
  unsigned short* Vh = (unsigned short*)smem;      // [128][64] swizzled
  unsigned short* Ph = Vh + 8192;                  // [128][64] swizzled

  const int rb = tid >> 3, jj = tid & 7;
  const int dst0 = rb*64 + ((jj ^ (rb & 7)) << 3);
  const long vbase = ((long)(b*C_IN + ct*128) + rb)*LSEQ + jj*8;
  const long pbase = ((long)b*LSEQ + lt*128 + rb)*LSEQ + jj*8;

  f32x4 acc[4][4] = {};
  short8 rv[4], rp[4];
  #pragma unroll
  for (int j = 0; j < 4; ++j) {
    rv[j] = *(const short8*)&vws[vbase + (long)j*32*LSEQ];
    rp[j] = *(const short8*)&pbuf[pbase + (long)j*32*LSEQ];
  }

  for (int mb = 0; mb < 16; ++mb) {
    __syncthreads();
    #pragma unroll
    for (int j = 0; j < 4; ++j) {
      *(short8*)&Vh[dst0 + j*2048] = rv[j];
      *(short8*)&Ph[dst0 + j*2048] = rp[j];
    }
    __syncthreads();
    if (mb < 15) {
      #pragma unroll
      for (int j = 0; j < 4; ++j) {
        rv[j] = *(const short8*)&vws[vbase + (mb+1)*64 + (long)j*32*LSEQ];
        rp[j] = *(const short8*)&pbuf[pbase + (mb+1)*64 + (long)j*32*LSEQ];
      }
    }
    #pragma unroll
    for (int ks = 0; ks < 2; ++ks) {
      int s = ((ks*4 + g) ^ (ln & 7)) << 3;
      short8 bf[4];
      #pragma unroll
      for (int ni = 0; ni < 4; ++ni) {
        int cr = wc*64 + ni*16 + ln;
        bf[ni] = *(const short8*)&Ph[cr*64 + s];
      }
      #pragma unroll
      for (int mi = 0; mi < 4; ++mi) {
        int ar = wr*64 + mi*16 + ln;
        short8 af = *(const short8*)&Vh[ar*64 + s];
        #pragma unroll
        for (int ni = 0; ni < 4; ++ni)
          acc[mi][ni] = __builtin_amdgcn_mfma_f32_16x16x32_bf16(af, bf[ni], acc[mi][ni], 0,0,0);
      }
    }
  }
  __syncthreads();
  unsigned short* Tr = (unsigned short*)smem;      // [128 c][136]
  float gm = gamma[0];
  #pragma unroll
  for (int mi = 0; mi < 4; ++mi)
    #pragma unroll
    for (int ni = 0; ni < 4; ++ni)
      #pragma unroll
      for (int j = 0; j < 4; ++j) {
        int rloc = wr*64 + mi*16 + g*4 + j;
        int cloc = wc*64 + ni*16 + ln;
        Tr[rloc*136 + cloc] = bf16_rn(acc[mi][ni][j]);
      }
  __syncthreads();
  #pragma unroll
  for (int i = 0; i < 8; ++i) {
    int idx = tid + i*256;
    int c = idx >> 4, s = idx & 15;
    short8 v8 = *(const short8*)&Tr[c*136 + s*8];
    long base = ((long)b*C_IN + ct*128 + c)*LSEQ + lt*128 + s*8;
    f32x4 x0 = *(const f32x4*)&x[base];
    f32x4 x1 = *(const f32x4*)&x[base + 4];
    f32x4 o0, o1;
    #pragma unroll
    for (int j = 0; j < 4; ++j) {
      o0[j] = gm * bf16_to_f32((unsigned short)v8[j]) + x0[j];
      o1[j] = gm * bf16_to_f32((unsigned short)v8[j+4]) + x1[j];
    }
    *(f32x4*)&out[base] = o0;
    *(f32x4*)&out[base + 4] = o1;
  }
}

extern "C" void kernel_launch(void* const* d_in, const int* in_sizes, int n_in,
                              void* d_out, int out_size, void* d_ws, size_t ws_size,
                              hipStream_t stream)
{
  const float* x  = (const float*)d_in[0];
  const float* Wq = (const float*)d_in[1];
  const float* bq = (const float*)d_in[2];
  const float* Wk = (const float*)d_in[3];
  const float* bk = (const float*)d_in[4];
  const float* Wv = (const float*)d_in[5];
  const float* bv = (const float*)d_in[6];
  const float* gamma = (const float*)d_in[7];
  float* out  = (float*)d_out;
  float* attn = out + OUT_ELEMS;

  char* ws = (char*)d_ws;
  unsigned short* Wqh = (unsigned short*)(ws + 0);
  unsigned short* Wql = (unsigned short*)(ws + 65536);
  unsigned short* Wkh = (unsigned short*)(ws + 131072);
  unsigned short* Wkl = (unsigned short*)(ws + 196608);
  unsigned short* Wvh = (unsigned short*)(ws + 262144);
  unsigned short* qhp = (unsigned short*)(ws + 786432);
  unsigned short* qlp = (unsigned short*)(ws + 786432 + 1ul*4194304);
  unsigned short* khp = (unsigned short*)(ws + 786432 + 2ul*4194304);
  unsigned short* klp = (unsigned short*)(ws + 786432 + 3ul*4194304);
  unsigned short* vws = (unsigned short*)(ws + 786432 + 4ul*4194304);
  // union region (lifetimes disjoint): xT planes (before energy_softmax) / pbuf (after)
  char* uni = ws + 786432 + 4ul*4194304 + 33554432;
  unsigned short* xth  = (unsigned short*)uni;                    // 32 MiB
  unsigned short* xtl  = (unsigned short*)(uni + 33554432);       // 32 MiB
  unsigned short* pbuf = (unsigned short*)uni;                    // 64 MiB

  split_weights<<<320, 256, 0, stream>>>(Wq, Wk, Wv, Wqh, Wql, Wkh, Wkl, Wvh);
  transpose_split<<<dim3(16, 8, B_SZ), 256, 0, stream>>>(x, xth, xtl);
  qk_proj<<<dim3(16, B_SZ), 256, 0, stream>>>(xth, xtl, Wqh, Wql, Wkh, Wkl, bq, bk, qhp, qlp, khp, klp);
  v_proj<<<dim3(8, 4, B_SZ), 256, 0, stream>>>(xth, Wvh, bv, vws);
  energy_softmax<<<dim3(64, B_SZ), 256, 0, stream>>>(qhp, qlp, khp, klp, attn, pbuf);
  pv_out<<<dim3(8, 4, B_SZ), 256, 0, stream>>>(vws, pbuf, x, gamma, out);
}